// Round 5
// baseline (300.009 us; speedup 1.0000x reference)
//
#include <hip/hip_runtime.h>

// OrthoLoss: scalar = BCE(y_zt,target) + lambda_od*(KL_t+KL_s) + lambda_e*Entropy(s_zt)
// B=65536, D=128. 257 MB read-once; ~131 MB misses to HBM (rest L3-hot from restore).
//
// Round-5 (R4 = 51.4 us, HBM 33%, occ 31%, VGPR=32 -> prefetch sunk, TLP half-used):
//  - GRID=2048, launch_bounds(256,8): 8 blocks/CU resident -> 32 waves/CU (2x TLP).
//  - sched_barrier(0) between prefetch-issue and compute: compiler cannot sink
//    next-iteration loads past it -> 4 loads genuinely in flight per wave under
//    every compute phase (R4's rotating buffer was folded away, VGPR=32).
//  - Keep: NT loads, t/s stream split by block parity, f64 partial per block.

#define B_SIZE 65536
#define D_SIZE 128
#define GRID   2048
#define BLOCK  256

#define L2E  1.44269504089f           // log2(e)
#define HL2E 0.72134752045f           // 0.5*log2(e)
#define SHIFT_L2E 57.7078016356f      // 40*log2(e)

typedef float vf4 __attribute__((ext_vector_type(4)));

__device__ __forceinline__ vf4 ntload(const float* p) {
    return __builtin_nontemporal_load((const vf4*)p);
}

__device__ __forceinline__ float red8(float v) {   // sum across 8-lane group
    v += __shfl_xor(v, 1, 64);
    v += __shfl_xor(v, 2, 64);
    v += __shfl_xor(v, 4, 64);
    return v;
}
__device__ __forceinline__ float red64(float v) {  // full-wave sum
#pragma unroll
    for (int m = 1; m <= 32; m <<= 1) v += __shfl_xor(v, m, 64);
    return v;
}

__global__ __launch_bounds__(BLOCK, 8) void ortho_main(
    const float* __restrict__ mean_t,   const float* __restrict__ mean_s,
    const float* __restrict__ log_std_t,const float* __restrict__ log_std_s,
    const float* __restrict__ y_zt,     const float* __restrict__ s_zt,
    const float* __restrict__ target,
    const float* __restrict__ noise_pt, const float* __restrict__ noise_ps,
    const float* __restrict__ noise_et, const float* __restrict__ noise_es,
    const int*  __restrict__ step,
    double* __restrict__ partial)
{
    const int lane = threadIdx.x & 63;
    const int wid  = threadIdx.x >> 6;          // wave in block (0..3)
    const int k    = lane & 7;                  // lane within 8-lane row group
    const int sub  = lane >> 3;                 // row within group (0..7)

    const int sflag = blockIdx.x & 1;           // 0 = t stream, 1 = s stream
    const int wave  = (blockIdx.x >> 1) * (BLOCK / 64) + wid;  // 0..4095 per stream

    const float* __restrict__ Am = sflag ? mean_s    : mean_t;
    const float* __restrict__ Al = sflag ? log_std_s : log_std_t;
    const float* __restrict__ An = sflag ? noise_es  : noise_et;
    const float* __restrict__ Ap = sflag ? noise_ps  : noise_pt;

    // prior mean: t = zeros with [13]=1 ; s = ones with [13]=0.
    // element d = j*32 + k*4 + c ; d==13 -> (j=0, k=3, c=1)
    const float pk3    = (k == 3) ? 1.0f : 0.0f;
    const float pm_def = sflag ? 1.0f : 0.0f;
    const float pm_y0  = sflag ? 1.0f - pk3 : pk3;   // c==1 slot at j==0

    // wave handles 2 consecutive row-groups (16 rows, 8 KB/array contiguous)
    const int off = (wave * 16 + sub) * D_SIZE + k * 4;   // rg adds 1024, j adds 32

    const float frac      = (float)step[0] * (1.0f / 30.0f);
    const float lambda_e  = 0.1f   * exp2f(frac);
    const float lambda_od = 0.036f * exp2f(frac * 0.13750352374993502f); // log2(1.1)

    float comb = 0.0f;

#define ELEM(SE, SP, SEP, MX, LX, NX, PX, PM)                         \
    {                                                                 \
        float e  = fmaf(exp2f((LX) * HL2E), (NX), (MX));              \
        float ex = exp2f(fmaf(e, L2E, -SHIFT_L2E));                   \
        float p  = (PM) + (PX);                                       \
        SE += ex;                                                     \
        SP += exp2f(p * L2E);                                         \
        SEP = fmaf(ex, e - p, SEP);                                   \
    }

    // software pipeline, depth 2, order pinned by sched_barrier(0):
    //   loads(it+1) | SB | compute(it)
    vf4 cm, cl, cn, cp, nm, nl, nn, nq;
    cm = ntload(Am + off); cl = ntload(Al + off);
    cn = ntload(An + off); cp = ntload(Ap + off);

    float se = 0.f, sp = 0.f, sep = 0.f;
#pragma unroll
    for (int it = 0; it < 8; ++it) {            // it = rg*4 + j
        const int j = it & 3;
        if (it < 7) {                           // prefetch next iteration
            const int it2 = it + 1;
            const int o2  = off + (it2 >> 2) * (8 * D_SIZE) + (it2 & 3) * 32;
            nm = ntload(Am + o2); nl = ntload(Al + o2);
            nn = ntload(An + o2); nq = ntload(Ap + o2);
        }
        __builtin_amdgcn_sched_barrier(0);      // don't sink the prefetch
        if (j == 0) { se = 0.f; sp = 0.f; sep = 0.f; }
        const float pmy = (j == 0) ? pm_y0 : pm_def;
        ELEM(se, sp, sep, cm.x, cl.x, cn.x, cp.x, pm_def)
        ELEM(se, sp, sep, cm.y, cl.y, cn.y, cp.y, pmy)
        ELEM(se, sp, sep, cm.z, cl.z, cn.z, cp.z, pm_def)
        ELEM(se, sp, sep, cm.w, cl.w, cn.w, cp.w, pm_def)
        if (j == 3) {                           // row-group complete: reduce
            float rse = red8(se), rsp = red8(sp), rsep = red8(sep);
            if (k == 0)
                comb += rsep / rse - 40.0f + (__logf(rsp) - __logf(rse));
        }
        cm = nm; cl = nl; cn = nn; cp = nq;     // rotate (renamed after unroll)
    }
#undef ELEM
    comb *= lambda_od;

    // ---------------- small terms: 32 rows of BCE + entropy per block
    if (threadIdx.x < 32) {
        const int b = blockIdx.x * 32 + threadIdx.x;
        const float y = y_zt[b];
        const float t = target[b];
        const float bce = fmaxf(y, 0.f) - y * t + __logf(1.0f + exp2f(-fabsf(y) * L2E));
        const float2 s = *(const float2*)(s_zt + 2 * (size_t)b);
        const float m   = fmaxf(s.x, s.y);
        const float lse = m + __logf(exp2f((s.x - m) * L2E) + exp2f((s.y - m) * L2E));
        const float l0 = s.x - lse, l1 = s.y - lse;
        const float ent = -(exp2f(l0 * L2E) * l0 + exp2f(l1 * L2E) * l1);
        comb += bce + lambda_e * ent;
    }

    // ---------------- block reduce -> one f64 partial per block
    comb = red64(comb);
    __shared__ float sm[BLOCK / 64];
    if (lane == 0) sm[wid] = comb;
    __syncthreads();
    if (threadIdx.x == 0) {
        float t0 = 0.f;
#pragma unroll
        for (int w = 0; w < BLOCK / 64; ++w) t0 += sm[w];
        partial[blockIdx.x] = (double)t0;
    }
}

__global__ void ortho_final(const double* __restrict__ partial,
                            float* __restrict__ out)
{
    double s = 0.0;
    for (int i = threadIdx.x; i < GRID; i += BLOCK) s += partial[i];
#pragma unroll
    for (int m = 1; m <= 32; m <<= 1) s += __shfl_xor(s, m, 64);
    __shared__ double sm[BLOCK / 64];
    const int lane = threadIdx.x & 63;
    const int wid  = threadIdx.x >> 6;
    if (lane == 0) sm[wid] = s;
    __syncthreads();
    if (threadIdx.x == 0) {
        double tot = 0.0;
#pragma unroll
        for (int w = 0; w < BLOCK / 64; ++w) tot += sm[w];
        out[0] = (float)(tot / (double)B_SIZE);
    }
}

extern "C" void kernel_launch(void* const* d_in, const int* in_sizes, int n_in,
                              void* d_out, int out_size, void* d_ws, size_t ws_size,
                              hipStream_t stream) {
    const float* mean_t    = (const float*)d_in[0];
    const float* mean_s    = (const float*)d_in[1];
    const float* log_std_t = (const float*)d_in[2];
    const float* log_std_s = (const float*)d_in[3];
    const float* y_zt      = (const float*)d_in[4];
    const float* s_zt      = (const float*)d_in[5];
    // d_in[6] s_zs, d_in[7] z1, d_in[8] z2: unused by the reference
    const float* target    = (const float*)d_in[9];
    const float* noise_pt  = (const float*)d_in[10];
    const float* noise_ps  = (const float*)d_in[11];
    const float* noise_et  = (const float*)d_in[12];
    const float* noise_es  = (const float*)d_in[13];
    const int*   step      = (const int*)d_in[14];

    double* partial = (double*)d_ws;   // 2048 doubles, all written every launch
    float*  out     = (float*)d_out;

    hipLaunchKernelGGL(ortho_main, dim3(GRID), dim3(BLOCK), 0, stream,
                       mean_t, mean_s, log_std_t, log_std_s,
                       y_zt, s_zt, target,
                       noise_pt, noise_ps, noise_et, noise_es, step, partial);
    hipLaunchKernelGGL(ortho_final, dim3(1), dim3(BLOCK), 0, stream, partial, out);
}